// Round 1
// baseline (204.230 us; speedup 1.0000x reference)
//
#include <hip/hip_runtime.h>
#include <stdint.h>

#define FEAT 1024
#define BATCH 4096
#define NTASK 8

typedef float f32x4 __attribute__((ext_vector_type(4)));
typedef short bf16x8 __attribute__((ext_vector_type(8)));
typedef unsigned short u16x8 __attribute__((ext_vector_type(8)));
typedef unsigned short u16x4 __attribute__((ext_vector_type(4)));

__device__ inline unsigned short f32_to_bf16(float f) {
  union { float f; uint32_t u; } v; v.f = f;
  uint32_t u = v.u;
  uint32_t lsb = (u >> 16) & 1u;
  u += 0x7fffu + lsb;  // round-to-nearest-even
  return (unsigned short)(u >> 16);
}

__device__ inline void gload_lds16(const void* g, void* l) {
  __builtin_amdgcn_global_load_lds(
      (__attribute__((address_space(1))) void*)(g),
      (__attribute__((address_space(3))) void*)(l),
      16, 0, 0);
}

// ---------------- elementwise f32 -> bf16 ----------------
__global__ void convert_f32_bf16(const float* __restrict__ in,
                                 unsigned short* __restrict__ out, int n8) {
  int i = blockIdx.x * blockDim.x + threadIdx.x;
  if (i >= n8) return;
  const float4* p = (const float4*)in + (size_t)i * 2;
  float4 a = p[0], b = p[1];
  u16x8 o;
  o[0] = f32_to_bf16(a.x); o[1] = f32_to_bf16(a.y);
  o[2] = f32_to_bf16(a.z); o[3] = f32_to_bf16(a.w);
  o[4] = f32_to_bf16(b.x); o[5] = f32_to_bf16(b.y);
  o[6] = f32_to_bf16(b.z); o[7] = f32_to_bf16(b.w);
  *((u16x8*)out + i) = o;
}

// ---------------- transpose+convert task mats: Mt[j][n][k] = bf16(M[j][k][n]) ----------------
__global__ void transpose_convert_M(const float* __restrict__ M,
                                    unsigned short* __restrict__ Mt) {
  const int j = blockIdx.z;
  const int n0 = blockIdx.x * 64;
  const int k0 = blockIdx.y * 64;
  const float* src = M + (size_t)j * FEAT * FEAT;
  unsigned short* dst = Mt + (size_t)j * FEAT * FEAT;
  __shared__ unsigned short Ts[64][68];  // padded rows: 136B
  const int t = threadIdx.x;
  // phase 1: coalesced read of 64(k) x 64(n) f32 tile, convert, store [k][n] in LDS
#pragma unroll
  for (int i = 0; i < 4; ++i) {
    int fidx = i * 256 + t;          // 0..1023 float4 chunks
    int kl = fidx >> 4;              // 0..63
    int nf = fidx & 15;              // 0..15
    float4 v = *(const float4*)(src + (size_t)(k0 + kl) * FEAT + n0 + nf * 4);
    u16x4 o;
    o[0] = f32_to_bf16(v.x); o[1] = f32_to_bf16(v.y);
    o[2] = f32_to_bf16(v.z); o[3] = f32_to_bf16(v.w);
    *(u16x4*)&Ts[kl][nf * 4] = o;
  }
  __syncthreads();
  // phase 2: read columns, write coalesced bf16 rows of Mt (rows = n, cols = k)
#pragma unroll
  for (int i = 0; i < 2; ++i) {
    int cidx = t * 2 + i;            // 0..511 chunks of 8
    int nl = cidx >> 3;              // 0..63
    int kc = (cidx & 7) * 8;         // 0..56
    u16x8 o;
#pragma unroll
    for (int r = 0; r < 8; ++r) o[r] = Ts[kc + r][nl];
    *(u16x8*)(dst + (size_t)(n0 + nl) * FEAT + k0 + kc) = o;
  }
}

// ---------------- GEMM: Y = A(bf16) @ B, B given as Bt[n][k] (bf16) ----------------
// MODE 0: xf[idx] = res[idx] + c * Y;  xbn[idx] = bf16(xf[idx])   (task step)
// MODE 1: xf[idx] = Y                                             (projection)
// Block tile 128(M) x 64(N), BK=64, 256 threads = 4 waves (2x2), wave tile 64x32.
template <int MODE>
__global__ __launch_bounds__(256, 2) void gemm_step(
    const unsigned short* __restrict__ A,    // [4096][1024] bf16
    const unsigned short* __restrict__ Bt,   // [1024][1024] bf16, rows=n cols=k
    const float* __restrict__ res,           // residual src (MODE 0)
    float* __restrict__ xf,                  // f32 out (x or final)
    unsigned short* __restrict__ xbn,        // bf16 out (MODE 0)
    const float* __restrict__ mean, const float* __restrict__ eps,
    const float* __restrict__ logvar, int j) {
  constexpr int K = FEAT;
  __shared__ __align__(16) unsigned short As[128 * 64];  // 16 KB, row=m, 128B/row, swizzled
  __shared__ __align__(16) unsigned short Bs[64 * 64];   // 8 KB,  row=n, 128B/row, swizzled

  const int t = threadIdx.x;
  const int lane = t & 63;
  const int wid = t >> 6;
  const int wm = wid >> 1;  // 0..1 : 64-row slab
  const int wn = wid & 1;   // 0..1 : 32-col slab
  const int bn = blockIdx.x;  // 0..15
  const int bm = blockIdx.y;  // 0..31

  f32x4 acc[4][2];
#pragma unroll
  for (int m = 0; m < 4; ++m)
#pragma unroll
    for (int n = 0; n < 2; ++n) acc[m][n] = (f32x4)0.f;

  // staging geometry: thread t covers 16B at linear LDS offset t*16 (+ 4KB per pass)
  // linear row = p*32 + (t>>3); byte-in-row cb = (t&7)*16
  // swizzle: logical colbyte = cb ^ ((row&7)<<4); row&7 == (t>>3)&7 (pass-invariant)
  const int ar = t >> 3;                                  // 0..31 base row
  const int acb = (((t & 7) ^ ((t >> 3) & 7)) << 4);      // pre-swizzled source colbyte
  const unsigned short* Abase = A + (size_t)(bm * 128 + ar) * K + (acb >> 1);
  const unsigned short* Bbase = Bt + (size_t)(bn * 64 + ar) * K + (acb >> 1);
  unsigned short* AsP = &As[t * 8];
  unsigned short* BsP = &Bs[t * 8];

  for (int kt = 0; kt < K / 64; ++kt) {
    const int ko = kt * 64;
    // stage A: 4 passes x 4KB
#pragma unroll
    for (int p = 0; p < 4; ++p)
      gload_lds16(Abase + (size_t)(p * 32) * K + ko, AsP + p * 2048);
    // stage B: 2 passes x 4KB
#pragma unroll
    for (int p = 0; p < 2; ++p)
      gload_lds16(Bbase + (size_t)(p * 32) * K + ko, BsP + p * 2048);
    __syncthreads();  // compiler drains vmcnt before barrier

#pragma unroll
    for (int kk = 0; kk < 2; ++kk) {
      bf16x8 a[4], b[2];
      const int cbase = kk * 64 + ((lane >> 4) << 4);  // logical colbyte of this lane's 8 k's
#pragma unroll
      for (int m = 0; m < 4; ++m) {
        int r = wm * 64 + m * 16 + (lane & 15);
        int cb = cbase ^ ((r & 7) << 4);
        a[m] = *(const bf16x8*)((const char*)As + r * 128 + cb);
      }
#pragma unroll
      for (int n = 0; n < 2; ++n) {
        int r = wn * 32 + n * 16 + (lane & 15);
        int cb = cbase ^ ((r & 7) << 4);
        b[n] = *(const bf16x8*)((const char*)Bs + r * 128 + cb);
      }
#pragma unroll
      for (int m = 0; m < 4; ++m)
#pragma unroll
        for (int n = 0; n < 2; ++n)
          acc[m][n] = __builtin_amdgcn_mfma_f32_16x16x32_bf16(a[m], b[n], acc[m][n], 0, 0, 0);
    }
    __syncthreads();
  }

  // epilogue. C/D layout: col = lane&15, row = (lane>>4)*4 + reg  [HW-verified]
  float c = 0.f;
  if (MODE == 0) {
    float lv = fminf(fmaxf(logvar[j], -8.f), 2.f);
    c = mean[j] + eps[j] * expf(0.5f * lv);
  }
#pragma unroll
  for (int m = 0; m < 4; ++m) {
    int Rb = bm * 128 + wm * 64 + m * 16 + ((lane >> 4) << 2);
#pragma unroll
    for (int n = 0; n < 2; ++n) {
      int C = bn * 64 + wn * 32 + n * 16 + (lane & 15);
#pragma unroll
      for (int r2 = 0; r2 < 4; ++r2) {
        size_t idx = (size_t)(Rb + r2) * FEAT + C;
        if (MODE == 0) {
          float v = res[idx] + c * acc[m][n][r2];
          xf[idx] = v;
          xbn[idx] = f32_to_bf16(v);
        } else {
          xf[idx] = acc[m][n][r2];
        }
      }
    }
  }
}

extern "C" void kernel_launch(void* const* d_in, const int* in_sizes, int n_in,
                              void* d_out, int out_size, void* d_ws, size_t ws_size,
                              hipStream_t stream) {
  const float* features = (const float*)d_in[0];
  const float* eps      = (const float*)d_in[1];
  const float* mean     = (const float*)d_in[2];
  const float* logvar   = (const float*)d_in[3];
  const float* task_mats= (const float*)d_in[4];
  const float* proj_w   = (const float*)d_in[5];
  float* out = (float*)d_out;

  uint8_t* ws = (uint8_t*)d_ws;
  unsigned short* Xb0 = (unsigned short*)(ws);                          // 8 MB
  unsigned short* Xb1 = (unsigned short*)(ws + ((size_t)8 << 20));      // 8 MB
  float*          Xf  = (float*)(ws + ((size_t)16 << 20));              // 16 MB
  unsigned short* Wb  = (unsigned short*)(ws + ((size_t)32 << 20));     // 2 MB
  unsigned short* Mt  = (unsigned short*)(ws + ((size_t)34 << 20));     // 16 MB

  // one-time conversions (graph replays them; all cheap & L3-resident)
  convert_f32_bf16<<<2048, 256, 0, stream>>>(features, Xb0, BATCH * FEAT / 8);
  convert_f32_bf16<<<512, 256, 0, stream>>>(proj_w, Wb, FEAT * FEAT / 8);
  transpose_convert_M<<<dim3(16, 16, 8), 256, 0, stream>>>(task_mats, Mt);

  unsigned short* xb[2] = {Xb0, Xb1};
  for (int j = 0; j < NTASK; ++j) {
    gemm_step<0><<<dim3(16, 32), 256, 0, stream>>>(
        xb[j & 1], Mt + (size_t)j * FEAT * FEAT,
        (j == 0) ? features : Xf, Xf, xb[(j + 1) & 1],
        mean, eps, logvar, j);
  }
  gemm_step<1><<<dim3(16, 32), 256, 0, stream>>>(
      Xb0, Wb, nullptr, out, nullptr, nullptr, nullptr, nullptr, 0);
}

// Round 2
// 164.902 us; speedup vs baseline: 1.2385x; 1.2385x over previous
//
#include <hip/hip_runtime.h>
#include <stdint.h>

#define FEAT 1024
#define BATCH 4096
#define NTASK 8

typedef float f32x4 __attribute__((ext_vector_type(4)));
typedef short bf16x8 __attribute__((ext_vector_type(8)));
typedef unsigned short u16x8 __attribute__((ext_vector_type(8)));
typedef unsigned short u16x4 __attribute__((ext_vector_type(4)));

__device__ inline unsigned short f32_to_bf16(float f) {
  union { float f; uint32_t u; } v; v.f = f;
  uint32_t u = v.u;
  uint32_t lsb = (u >> 16) & 1u;
  u += 0x7fffu + lsb;  // round-to-nearest-even
  return (unsigned short)(u >> 16);
}

__device__ inline float bf16_to_f32(unsigned short h) {
  union { uint32_t u; float f; } v; v.u = (uint32_t)h << 16; return v.f;
}

__device__ inline void gload_lds16(const void* g, void* l) {
  __builtin_amdgcn_global_load_lds(
      (__attribute__((address_space(1))) void*)(g),
      (__attribute__((address_space(3))) void*)(l),
      16, 0, 0);
}

// ---------------- fused elementwise f32 -> bf16 for two buffers ----------------
__global__ void convert_two(const float* __restrict__ a, unsigned short* __restrict__ oa, int n8a,
                            const float* __restrict__ b, unsigned short* __restrict__ ob, int n8b) {
  int i = blockIdx.x * blockDim.x + threadIdx.x;
  const float* in;
  unsigned short* out;
  if (i < n8a) { in = a; out = oa; }
  else if (i < n8a + n8b) { in = b; out = ob; i -= n8a; }
  else return;
  const float4* p = (const float4*)in + (size_t)i * 2;
  float4 x = p[0], y = p[1];
  u16x8 o;
  o[0] = f32_to_bf16(x.x); o[1] = f32_to_bf16(x.y);
  o[2] = f32_to_bf16(x.z); o[3] = f32_to_bf16(x.w);
  o[4] = f32_to_bf16(y.x); o[5] = f32_to_bf16(y.y);
  o[6] = f32_to_bf16(y.z); o[7] = f32_to_bf16(y.w);
  *((u16x8*)out + i) = o;
}

// ---------------- transpose+convert task mats: Mt[j][n][k] = bf16(M[j][k][n]) ----------------
__global__ void transpose_convert_M(const float* __restrict__ M,
                                    unsigned short* __restrict__ Mt) {
  const int j = blockIdx.z;
  const int n0 = blockIdx.x * 64;
  const int k0 = blockIdx.y * 64;
  const float* src = M + (size_t)j * FEAT * FEAT;
  unsigned short* dst = Mt + (size_t)j * FEAT * FEAT;
  __shared__ unsigned short Ts[64][68];  // padded rows: 136B
  const int t = threadIdx.x;
#pragma unroll
  for (int i = 0; i < 4; ++i) {
    int fidx = i * 256 + t;
    int kl = fidx >> 4;
    int nf = fidx & 15;
    float4 v = *(const float4*)(src + (size_t)(k0 + kl) * FEAT + n0 + nf * 4);
    u16x4 o;
    o[0] = f32_to_bf16(v.x); o[1] = f32_to_bf16(v.y);
    o[2] = f32_to_bf16(v.z); o[3] = f32_to_bf16(v.w);
    *(u16x4*)&Ts[kl][nf * 4] = o;
  }
  __syncthreads();
#pragma unroll
  for (int i = 0; i < 2; ++i) {
    int cidx = t * 2 + i;
    int nl = cidx >> 3;
    int kc = (cidx & 7) * 8;
    u16x8 o;
#pragma unroll
    for (int r = 0; r < 8; ++r) o[r] = Ts[kc + r][nl];
    *(u16x8*)(dst + (size_t)(n0 + nl) * FEAT + k0 + kc) = o;
  }
}

// ---------------- GEMM: Y = A(bf16) @ B, B given as Bt[n][k] (bf16) ----------------
// MODE 0: xbn[idx] = bf16(f32(A[idx]) + c * Y)   (task step, x carried in bf16)
// MODE 1: out[idx] = Y                           (projection, f32 out)
// Block tile 128(M) x 64(N), BK=64, 256 threads = 4 waves (2x2), wave tile 64x32.
template <int MODE>
__global__ __launch_bounds__(256, 2) void gemm_step(
    const unsigned short* __restrict__ A,    // [4096][1024] bf16 (also residual src)
    const unsigned short* __restrict__ Bt,   // [1024][1024] bf16, rows=n cols=k
    float* __restrict__ outf,                // f32 out (MODE 1)
    unsigned short* __restrict__ xbn,        // bf16 out (MODE 0)
    const float* __restrict__ mean, const float* __restrict__ eps,
    const float* __restrict__ logvar, int j) {
  constexpr int K = FEAT;
  __shared__ __align__(16) unsigned short As[128 * 64];  // 16 KB, row=m, 128B/row, swizzled
  __shared__ __align__(16) unsigned short Bs[64 * 64];   // 8 KB,  row=n, 128B/row, swizzled

  const int t = threadIdx.x;
  const int lane = t & 63;
  const int wid = t >> 6;
  const int wm = wid >> 1;
  const int wn = wid & 1;

  // XCD-aware swizzle: 512 blocks, 8 XCDs -> each XCD gets 64 consecutive
  // work items = 4 full A row-panels (1 MB A + 2 MB B per-XCD L2 footprint).
  const int lid = blockIdx.y * 16 + blockIdx.x;       // 0..511 (dispatch order)
  const int swz = (lid & 7) * 64 + (lid >> 3);        // bijective (512 % 8 == 0)
  const int bm = swz >> 4;                            // 0..31
  const int bn = swz & 15;                            // 0..15

  f32x4 acc[4][2];
#pragma unroll
  for (int m = 0; m < 4; ++m)
#pragma unroll
    for (int n = 0; n < 2; ++n) acc[m][n] = (f32x4)0.f;

  // staging geometry: thread t covers 16B at linear LDS offset t*16 (+ 4KB per pass)
  // linear row = p*32 + (t>>3); byte-in-row cb = (t&7)*16
  // swizzle: logical colbyte = cb ^ ((row&7)<<4); row&7 == (t>>3)&7 (pass-invariant)
  const int ar = t >> 3;
  const int acb = (((t & 7) ^ ((t >> 3) & 7)) << 4);
  const unsigned short* Abase = A + (size_t)(bm * 128 + ar) * K + (acb >> 1);
  const unsigned short* Bbase = Bt + (size_t)(bn * 64 + ar) * K + (acb >> 1);
  unsigned short* AsP = &As[t * 8];
  unsigned short* BsP = &Bs[t * 8];

  for (int kt = 0; kt < K / 64; ++kt) {
    const int ko = kt * 64;
#pragma unroll
    for (int p = 0; p < 4; ++p)
      gload_lds16(Abase + (size_t)(p * 32) * K + ko, AsP + p * 2048);
#pragma unroll
    for (int p = 0; p < 2; ++p)
      gload_lds16(Bbase + (size_t)(p * 32) * K + ko, BsP + p * 2048);
    __syncthreads();

#pragma unroll
    for (int kk = 0; kk < 2; ++kk) {
      bf16x8 a[4], b[2];
      const int cbase = kk * 64 + ((lane >> 4) << 4);
#pragma unroll
      for (int m = 0; m < 4; ++m) {
        int r = wm * 64 + m * 16 + (lane & 15);
        int cb = cbase ^ ((r & 7) << 4);
        a[m] = *(const bf16x8*)((const char*)As + r * 128 + cb);
      }
#pragma unroll
      for (int n = 0; n < 2; ++n) {
        int r = wn * 32 + n * 16 + (lane & 15);
        int cb = cbase ^ ((r & 7) << 4);
        b[n] = *(const bf16x8*)((const char*)Bs + r * 128 + cb);
      }
#pragma unroll
      for (int m = 0; m < 4; ++m)
#pragma unroll
        for (int n = 0; n < 2; ++n)
          acc[m][n] = __builtin_amdgcn_mfma_f32_16x16x32_bf16(a[m], b[n], acc[m][n], 0, 0, 0);
    }
    __syncthreads();
  }

  // epilogue. C/D layout: col = lane&15, row = (lane>>4)*4 + reg  [HW-verified]
  float c = 0.f;
  if (MODE == 0) {
    float lv = fminf(fmaxf(logvar[j], -8.f), 2.f);
    c = mean[j] + eps[j] * expf(0.5f * lv);
  }
#pragma unroll
  for (int m = 0; m < 4; ++m) {
    int Rb = bm * 128 + wm * 64 + m * 16 + ((lane >> 4) << 2);
#pragma unroll
    for (int n = 0; n < 2; ++n) {
      int C = bn * 64 + wn * 32 + n * 16 + (lane & 15);
#pragma unroll
      for (int r2 = 0; r2 < 4; ++r2) {
        size_t idx = (size_t)(Rb + r2) * FEAT + C;
        if (MODE == 0) {
          float v = bf16_to_f32(A[idx]) + c * acc[m][n][r2];
          xbn[idx] = f32_to_bf16(v);
        } else {
          outf[idx] = acc[m][n][r2];
        }
      }
    }
  }
}

extern "C" void kernel_launch(void* const* d_in, const int* in_sizes, int n_in,
                              void* d_out, int out_size, void* d_ws, size_t ws_size,
                              hipStream_t stream) {
  const float* features = (const float*)d_in[0];
  const float* eps      = (const float*)d_in[1];
  const float* mean     = (const float*)d_in[2];
  const float* logvar   = (const float*)d_in[3];
  const float* task_mats= (const float*)d_in[4];
  const float* proj_w   = (const float*)d_in[5];
  float* out = (float*)d_out;

  uint8_t* ws = (uint8_t*)d_ws;
  unsigned short* Xb0 = (unsigned short*)(ws);                          // 8 MB
  unsigned short* Xb1 = (unsigned short*)(ws + ((size_t)8 << 20));      // 8 MB
  unsigned short* Wb  = (unsigned short*)(ws + ((size_t)16 << 20));     // 2 MB
  unsigned short* Mt  = (unsigned short*)(ws + ((size_t)18 << 20));     // 16 MB

  // one-time conversions
  convert_two<<<2560, 256, 0, stream>>>(features, Xb0, BATCH * FEAT / 8,
                                        proj_w, Wb, FEAT * FEAT / 8);
  transpose_convert_M<<<dim3(16, 16, 8), 256, 0, stream>>>(task_mats, Mt);

  unsigned short* xb[2] = {Xb0, Xb1};
  for (int j = 0; j < NTASK; ++j) {
    gemm_step<0><<<dim3(16, 32), 256, 0, stream>>>(
        xb[j & 1], Mt + (size_t)j * FEAT * FEAT,
        nullptr, xb[(j + 1) & 1],
        mean, eps, logvar, j);
  }
  gemm_step<1><<<dim3(16, 32), 256, 0, stream>>>(
      Xb0, Wb, out, nullptr, nullptr, nullptr, nullptr, 0);
}

// Round 3
// 109.133 us; speedup vs baseline: 1.8714x; 1.5110x over previous
//
#include <hip/hip_runtime.h>
#include <stdint.h>

#define FEAT 1024
#define BATCH 4096
#define NTASK 8
#define S_ELEMS (1024 * 1024)

typedef float f32x4 __attribute__((ext_vector_type(4)));
typedef short bf16x8 __attribute__((ext_vector_type(8)));
typedef unsigned short u16x8 __attribute__((ext_vector_type(8)));
typedef unsigned short u16x4 __attribute__((ext_vector_type(4)));

__device__ inline unsigned short f32_to_bf16(float f) {
  union { float f; uint32_t u; } v; v.f = f;
  uint32_t u = v.u;
  uint32_t lsb = (u >> 16) & 1u;
  u += 0x7fffu + lsb;  // round-to-nearest-even
  return (unsigned short)(u >> 16);
}

__device__ inline float bf16_to_f32(unsigned short h) {
  union { uint32_t u; float f; } v; v.u = (uint32_t)h << 16; return v.f;
}

__device__ inline void gload_lds16(const void* g, void* l) {
  __builtin_amdgcn_global_load_lds(
      (__attribute__((address_space(1))) void*)(g),
      (__attribute__((address_space(3))) void*)(l),
      16, 0, 0);
}

// ---------------- fused elementwise f32 -> bf16 for two buffers ----------------
__global__ void convert_two(const float* __restrict__ a, unsigned short* __restrict__ oa, int n8a,
                            const float* __restrict__ b, unsigned short* __restrict__ ob, int n8b) {
  int i = blockIdx.x * blockDim.x + threadIdx.x;
  const float* in;
  unsigned short* out;
  if (i < n8a) { in = a; out = oa; }
  else if (i < n8a + n8b) { in = b; out = ob; i -= n8a; }
  else return;
  const float4* p = (const float4*)in + (size_t)i * 2;
  float4 x = p[0], y = p[1];
  u16x8 o;
  o[0] = f32_to_bf16(x.x); o[1] = f32_to_bf16(x.y);
  o[2] = f32_to_bf16(x.z); o[3] = f32_to_bf16(x.w);
  o[4] = f32_to_bf16(y.x); o[5] = f32_to_bf16(y.y);
  o[6] = f32_to_bf16(y.z); o[7] = f32_to_bf16(y.w);
  *((u16x8*)out + i) = o;
}

// ---------------- Dr[j][k][n] = bf16(c_j*M_j[k][n]);  Dt[j][n][k] = same transposed ----------------
__global__ void delta_convert(const float* __restrict__ M,
                              const float* __restrict__ mean, const float* __restrict__ eps,
                              const float* __restrict__ logvar,
                              unsigned short* __restrict__ Dr, unsigned short* __restrict__ Dt) {
  const int j = blockIdx.z;
  float lv = fminf(fmaxf(logvar[j], -8.f), 2.f);
  const float c = mean[j] + eps[j] * expf(0.5f * lv);
  const int n0 = blockIdx.x * 64;
  const int k0 = blockIdx.y * 64;
  const float* src = M + (size_t)j * S_ELEMS;
  unsigned short* dr = Dr + (size_t)j * S_ELEMS;
  unsigned short* dt = Dt + (size_t)j * S_ELEMS;
  __shared__ unsigned short Ts[64][68];  // padded rows
  const int t = threadIdx.x;
#pragma unroll
  for (int i = 0; i < 4; ++i) {
    int fidx = i * 256 + t;
    int kl = fidx >> 4;
    int nf = fidx & 15;
    float4 v = *(const float4*)(src + (size_t)(k0 + kl) * FEAT + n0 + nf * 4);
    u16x4 o;
    o[0] = f32_to_bf16(c * v.x); o[1] = f32_to_bf16(c * v.y);
    o[2] = f32_to_bf16(c * v.z); o[3] = f32_to_bf16(c * v.w);
    *(u16x4*)&Ts[kl][nf * 4] = o;
    *(u16x4*)(dr + (size_t)(k0 + kl) * FEAT + n0 + nf * 4) = o;
  }
  __syncthreads();
#pragma unroll
  for (int i = 0; i < 2; ++i) {
    int cidx = t * 2 + i;
    int nl = cidx >> 3;
    int kc = (cidx & 7) * 8;
    u16x8 o;
#pragma unroll
    for (int r = 0; r < 8; ++r) o[r] = Ts[kc + r][nl];
    *(u16x8*)(dt + (size_t)(n0 + nl) * FEAT + k0 + kc) = o;
  }
}

// ---------------- GEMM Y[r][C] = sum_k A[r][k]*Bt[C][k], 128x64 tile, BK=64, 4 waves ----------------
// MODE 0 (pair-compose, z slices): P = Y + addA + addB; write Pr (row-major bf16) + Pt (transposed bf16)
// MODE 1 (S-build): St[n][k] = bf16(Y[k][n] + W[n][k])   (S = W^T + Y), transposed-only write
// MODE 2 (big out): outf = Y (f32)
template <int MODE>
__global__ __launch_bounds__(256, 2) void gemm_tree(
    const unsigned short* __restrict__ A, const unsigned short* __restrict__ Bt,
    const unsigned short* __restrict__ addA, const unsigned short* __restrict__ addB,
    const float* __restrict__ Wf,
    unsigned short* __restrict__ Pr, unsigned short* __restrict__ Pt,
    float* __restrict__ outf) {
  constexpr int K = FEAT;
  __shared__ __align__(16) unsigned short As[128 * 64];  // 16 KB, swizzled
  __shared__ __align__(16) unsigned short Bs[64 * 64];   // 8 KB, swizzled

  const int t = threadIdx.x;
  const int lane = t & 63;
  const int wid = t >> 6;
  const int wm = wid >> 1;
  const int wn = wid & 1;

  // XCD-aware bijective swizzle over the 1-D grid (grid % 8 == 0 in all uses)
  const int nb = (int)gridDim.x;
  const int cpx = nb >> 3;
  const int lid = blockIdx.x;
  const int swzb = (lid & 7) * cpx + (lid >> 3);

  int bm, bn;
  const unsigned short *Ap, *Btp, *aA, *aB;
  unsigned short *pr, *pt;
  if (MODE == 0) {
    const int z = swzb >> 7;          // slice (128 blocks per 1024x1024 slice)
    const int rem = swzb & 127;
    bm = rem >> 4;                    // 0..7
    bn = rem & 15;                    // 0..15
    const size_t zo = (size_t)z * 2 * S_ELEMS;
    Ap = A + zo; aA = addA + zo;
    Btp = Bt + zo; aB = addB + zo;
    pr = Pr + (size_t)z * S_ELEMS;
    pt = Pt + (size_t)z * S_ELEMS;
  } else {
    bm = swzb >> 4;                   // MODE1: 0..7, MODE2: 0..31
    bn = swzb & 15;
    Ap = A; Btp = Bt; aA = nullptr; aB = nullptr; pr = Pr; pt = Pt;
  }

  f32x4 acc[4][2];
#pragma unroll
  for (int m = 0; m < 4; ++m)
#pragma unroll
    for (int n = 0; n < 2; ++n) acc[m][n] = (f32x4)0.f;

  // staging: thread t covers 16B at linear LDS offset t*16 (+4KB per pass)
  // swizzle: logical colbyte = cb ^ ((row&7)<<4); pre-swizzled on global source
  const int ar = t >> 3;
  const int acb = (((t & 7) ^ ((t >> 3) & 7)) << 4);
  const unsigned short* Abase = Ap + (size_t)(bm * 128 + ar) * K + (acb >> 1);
  const unsigned short* Bbase = Btp + (size_t)(bn * 64 + ar) * K + (acb >> 1);
  unsigned short* AsP = &As[t * 8];
  unsigned short* BsP = &Bs[t * 8];

  for (int kt = 0; kt < K / 64; ++kt) {
    const int ko = kt * 64;
#pragma unroll
    for (int p = 0; p < 4; ++p)
      gload_lds16(Abase + (size_t)(p * 32) * K + ko, AsP + p * 2048);
#pragma unroll
    for (int p = 0; p < 2; ++p)
      gload_lds16(Bbase + (size_t)(p * 32) * K + ko, BsP + p * 2048);
    __syncthreads();

#pragma unroll
    for (int kk = 0; kk < 2; ++kk) {
      bf16x8 a[4], b[2];
      const int cbase = kk * 64 + ((lane >> 4) << 4);
#pragma unroll
      for (int m = 0; m < 4; ++m) {
        int r = wm * 64 + m * 16 + (lane & 15);
        int cb = cbase ^ ((r & 7) << 4);
        a[m] = *(const bf16x8*)((const char*)As + r * 128 + cb);
      }
#pragma unroll
      for (int n = 0; n < 2; ++n) {
        int r = wn * 32 + n * 16 + (lane & 15);
        int cb = cbase ^ ((r & 7) << 4);
        b[n] = *(const bf16x8*)((const char*)Bs + r * 128 + cb);
      }
#pragma unroll
      for (int m = 0; m < 4; ++m)
#pragma unroll
        for (int n = 0; n < 2; ++n)
          acc[m][n] = __builtin_amdgcn_mfma_f32_16x16x32_bf16(a[m], b[n], acc[m][n], 0, 0, 0);
    }
    __syncthreads();
  }

  // epilogue. C/D layout: col = lane&15, row = (lane>>4)*4 + reg  [HW-verified]
#pragma unroll
  for (int m = 0; m < 4; ++m) {
    int Rb = bm * 128 + wm * 64 + m * 16 + ((lane >> 4) << 2);
#pragma unroll
    for (int n = 0; n < 2; ++n) {
      int C = bn * 64 + wn * 32 + n * 16 + (lane & 15);
      if (MODE == 0) {
        u16x4 tp;
#pragma unroll
        for (int r2 = 0; r2 < 4; ++r2) {
          size_t idx = (size_t)(Rb + r2) * FEAT + C;
          float v = acc[m][n][r2] + bf16_to_f32(aA[idx]) + bf16_to_f32(aB[idx]);
          unsigned short h = f32_to_bf16(v);
          pr[idx] = h;
          tp[r2] = h;
        }
        *(u16x4*)(pt + (size_t)C * FEAT + Rb) = tp;  // Pt[n][k], 8B store
      } else if (MODE == 1) {
        u16x4 tp;
#pragma unroll
        for (int r2 = 0; r2 < 4; ++r2) {
          float v = acc[m][n][r2] + Wf[(size_t)C * FEAT + (Rb + r2)];  // + W^T[row][C]
          tp[r2] = f32_to_bf16(v);
        }
        *(u16x4*)(pt + (size_t)C * FEAT + Rb) = tp;  // St[n][k]
      } else {
#pragma unroll
        for (int r2 = 0; r2 < 4; ++r2)
          outf[(size_t)(Rb + r2) * FEAT + C] = acc[m][n][r2];
      }
    }
  }
}

extern "C" void kernel_launch(void* const* d_in, const int* in_sizes, int n_in,
                              void* d_out, int out_size, void* d_ws, size_t ws_size,
                              hipStream_t stream) {
  const float* features = (const float*)d_in[0];
  const float* eps      = (const float*)d_in[1];
  const float* mean     = (const float*)d_in[2];
  const float* logvar   = (const float*)d_in[3];
  const float* task_mats= (const float*)d_in[4];
  const float* proj_w   = (const float*)d_in[5];
  float* out = (float*)d_out;

  // workspace aliasing (launch-ordered lifetimes), peak 48 MB:
  uint8_t* ws = (uint8_t*)d_ws;
  unsigned short* Dr  = (unsigned short*)(ws);                          //  0..16M (dead after L1)
  unsigned short* Dt  = (unsigned short*)(ws + ((size_t)16 << 20));     // 16..32M (dead after L1)
  unsigned short* P1r = (unsigned short*)(ws + ((size_t)32 << 20));     // 32..40M (dead after L2)
  unsigned short* P1t = (unsigned short*)(ws + ((size_t)40 << 20));     // 40..48M (dead after L2)
  unsigned short* P2r = (unsigned short*)(ws);                          //  0..4M  (over dead Dr)
  unsigned short* P2t = (unsigned short*)(ws + ((size_t)4 << 20));      //  4..8M
  unsigned short* P3r = (unsigned short*)(ws + ((size_t)8 << 20));      //  8..10M
  unsigned short* P3t = (unsigned short*)(ws + ((size_t)14 << 20));     // 14..16M (written, unused)
  unsigned short* St  = (unsigned short*)(ws + ((size_t)10 << 20));     // 10..12M
  unsigned short* Wb  = (unsigned short*)(ws + ((size_t)12 << 20));     // 12..14M
  unsigned short* Xb  = (unsigned short*)(ws + ((size_t)32 << 20));     // 32..40M (over dead P1r)

  // deltas: Dr/Dt[j] = c_j * M_j
  delta_convert<<<dim3(16, 16, 8), 256, 0, stream>>>(task_mats, mean, eps, logvar, Dr, Dt);

  // L1: 4 pair-composes batched (512 blocks): P1[z] = D[2z] + D[2z+1] + D[2z]@D[2z+1]
  gemm_tree<0><<<512, 256, 0, stream>>>(Dr, Dt + S_ELEMS, Dr, Dr + S_ELEMS,
                                        nullptr, P1r, P1t, nullptr);
  // L2: 2 composes (256 blocks)
  gemm_tree<0><<<256, 256, 0, stream>>>(P1r, P1t + S_ELEMS, P1r, P1r + S_ELEMS,
                                        nullptr, P2r, P2t, nullptr);
  // converts (Xb overlays dead P1r after L2; Wb overlays dead Dr)
  convert_two<<<2560, 256, 0, stream>>>(features, Xb, BATCH * FEAT / 8,
                                        proj_w, Wb, FEAT * FEAT / 8);
  // L3: final compose (128 blocks): P3 = P2[0] + P2[1] + P2[0]@P2[1]
  gemm_tree<0><<<128, 256, 0, stream>>>(P2r, P2t + S_ELEMS, P2r, P2r + S_ELEMS,
                                        nullptr, P3r, P3t, nullptr);
  // L4: St = (W^T + P3@W^T) transposed (128 blocks)
  gemm_tree<1><<<128, 256, 0, stream>>>(P3r, Wb, nullptr, nullptr, proj_w,
                                        nullptr, St, nullptr);
  // L5: out = x @ S (512 blocks, f32 out)
  gemm_tree<2><<<512, 256, 0, stream>>>(Xb, St, nullptr, nullptr, nullptr,
                                        nullptr, nullptr, out);
}